// Round 1
// baseline (2372.718 us; speedup 1.0000x reference)
//
#include <hip/hip_runtime.h>

// Parallel-beam forward projection (Radon transform).
// x: [B,1,512,512] f32 -> sino: [B,1,512,512] f32
// For view v, bin s: integrate img along ray p = s*(ct,st) + t*(-st,ct), 512 unit steps,
// bilinear interpolation with zero outside the image.

#define N_IMG 512
#define N_VIEWS 512
#define N_BINS 512

__device__ __forceinline__ float tap(const float* __restrict__ im, int xx, int yy) {
    // Reference: valid = in-bounds on the UNCLIPPED indices; read at clipped; select.
    bool valid = ((unsigned)xx < (unsigned)N_IMG) & ((unsigned)yy < (unsigned)N_IMG);
    int xc = min(max(xx, 0), N_IMG - 1);
    int yc = min(max(yy, 0), N_IMG - 1);
    float val = im[yc * N_IMG + xc];
    return valid ? val : 0.0f;
}

__global__ __launch_bounds__(N_BINS) void radon_fp_kernel(const float* __restrict__ img,
                                                          float* __restrict__ out) {
    const int v = blockIdx.x;   // view index
    const int b = blockIdx.y;   // batch index
    const int bin = threadIdx.x;

    // theta = v * fl32(double(pi)/512)  -- matches np.pi / nViews rounding
    const float dth = (float)(3.14159265358979323846 / (double)N_VIEWS);
    const float theta = (float)v * dth;
    float st, ct;
    sincosf(theta, &st, &ct);

    const float c = (float)(N_IMG - 1) * 0.5f;            // 255.5
    const float s = (float)bin - (float)(N_BINS - 1) * 0.5f;

    const float xs = fmaf(s, ct, c);   // x at t=0 offset
    const float ys = fmaf(s, st, c);

    const float* __restrict__ im = img + (size_t)b * (N_IMG * N_IMG);

    float acc = 0.0f;
#pragma unroll 4
    for (int t = 0; t < N_IMG; ++t) {
        const float tt = (float)t - (float)(N_IMG - 1) * 0.5f;
        const float x = fmaf(-tt, st, xs);
        const float y = fmaf(tt, ct, ys);
        const float x0 = floorf(x);
        const float y0 = floorf(y);
        const float wx = x - x0;
        const float wy = y - y0;
        const int xi = (int)x0;
        const int yi = (int)y0;

        const float v00 = tap(im, xi,     yi);
        const float v10 = tap(im, xi + 1, yi);
        const float v01 = tap(im, xi,     yi + 1);
        const float v11 = tap(im, xi + 1, yi + 1);

        // bilinear: lerp in x then y
        const float a0 = fmaf(v10 - v00, wx, v00);
        const float a1 = fmaf(v11 - v01, wx, v01);
        acc += fmaf(a1 - a0, wy, a0);
    }

    out[((size_t)b * N_VIEWS + v) * N_BINS + bin] = acc;
}

extern "C" void kernel_launch(void* const* d_in, const int* in_sizes, int n_in,
                              void* d_out, int out_size, void* d_ws, size_t ws_size,
                              hipStream_t stream) {
    const float* img = (const float*)d_in[0];
    float* out = (float*)d_out;
    const int B = in_sizes[0] / (N_IMG * N_IMG);
    dim3 grid(N_VIEWS, B);
    radon_fp_kernel<<<grid, N_BINS, 0, stream>>>(img, out);
}

// Round 7
// 1176.779 us; speedup vs baseline: 2.0163x; 2.0163x over previous
//
#include <hip/hip_runtime.h>

// Parallel-beam forward projection (Radon transform), LDS-tiled.
// x: [B,1,512,512] f32 -> sino: [B,1,512,512] f32
// Block = (view, batch, 64-bin s-tile). Loop over 8 chunks of 64 t-steps;
// stage the rotated footprint's bounding box (<=92x92, tile 96x96, pitch 97)
// into LDS, then bilinear-gather from LDS. Out-of-image cells are stored as
// 0 in LDS, exactly matching the reference's valid-mask semantics.

#define N_IMG 512
#define N_VIEWS 512
#define N_BINS 512
#define SB 64      // bins per block
#define TC 64      // t-steps per chunk
#define NCH (N_IMG / TC)
#define TDIM 96    // staged tile dim (>= 92 + margin)
#define PITCH 97   // odd pitch: decorrelates LDS banks for all angles

__global__ __launch_bounds__(256) void radon_fp_tiled(const float* __restrict__ img,
                                                      float* __restrict__ out) {
    __shared__ float tile[TDIM * PITCH];
    __shared__ float red[4][SB];

    const int v     = blockIdx.x;   // view
    const int b     = blockIdx.y;   // batch
    const int stile = blockIdx.z;   // s-tile (0..7)
    const int tid   = threadIdx.x;
    const int binl  = tid & 63;     // bin within tile
    const int g     = tid >> 6;     // t-group (0..3)

    const float dth = (float)(3.14159265358979323846 / (double)N_VIEWS);
    float st, ct;
    sincosf((float)v * dth, &st, &ct);

    const float c = (float)(N_IMG - 1) * 0.5f;              // 255.5
    const float s = (float)(stile * SB + binl) - (float)(N_BINS - 1) * 0.5f;

    const float* __restrict__ im = img + (size_t)b * (N_IMG * N_IMG);

    float acc = 0.0f;

    for (int ch = 0; ch < NCH; ++ch) {
        // ---- bounding box of this (s-tile, t-chunk) footprint (block-uniform) ----
        const float sA = (float)(stile * SB) - (float)(N_BINS - 1) * 0.5f;
        const float sBv = sA + (float)(SB - 1);
        const float tA = (float)(ch * TC) - (float)(N_IMG - 1) * 0.5f;
        const float tB = tA + (float)(TC - 1);

        const float xs[4] = { sA * ct - tA * st, sA * ct - tB * st,
                              sBv * ct - tA * st, sBv * ct - tB * st };
        const float ys[4] = { sA * st + tA * ct, sA * st + tB * ct,
                              sBv * st + tA * ct, sBv * st + tB * ct };
        const float xmin = fminf(fminf(xs[0], xs[1]), fminf(xs[2], xs[3])) + c;
        const float ymin = fminf(fminf(ys[0], ys[1]), fminf(ys[2], ys[3])) + c;
        const int X0 = (int)floorf(xmin) - 1;   // -1 margin for fp slop
        const int Y0 = (int)floorf(ymin) - 1;

        __syncthreads();   // make sure previous chunk's reads are done

        // ---- stage TDIM x TDIM cells, zero outside the image ----
        for (int idx = tid; idx < TDIM * TDIM; idx += 256) {
            const int r  = idx / TDIM;
            const int cc = idx - r * TDIM;
            const int gx = X0 + cc;
            const int gy = Y0 + r;
            float val = 0.0f;
            if ((unsigned)gx < (unsigned)N_IMG && (unsigned)gy < (unsigned)N_IMG)
                val = im[(gy << 9) + gx];
            tile[r * PITCH + cc] = val;
        }
        __syncthreads();

        // ---- 16 t-steps per thread from LDS ----
        const float xbase = fmaf(s, ct, c - (float)X0);
        const float ybase = fmaf(s, st, c - (float)Y0);
        const int tb = ch * TC + g * 16;
#pragma unroll
        for (int j = 0; j < 16; ++j) {
            const float tt = (float)(tb + j) - (float)(N_IMG - 1) * 0.5f;
            const float xl = fmaf(-tt, st, xbase);
            const float yl = fmaf(tt, ct, ybase);
            const float x0 = floorf(xl);
            const float y0 = floorf(yl);
            const float wx = xl - x0;
            const float wy = yl - y0;
            const int xi = (int)x0;
            const int yi = (int)y0;
            const float* p = &tile[yi * PITCH + xi];
            const float v00 = p[0];
            const float v10 = p[1];
            const float v01 = p[PITCH];
            const float v11 = p[PITCH + 1];
            const float a0 = fmaf(v10 - v00, wx, v00);
            const float a1 = fmaf(v11 - v01, wx, v01);
            acc += fmaf(a1 - a0, wy, a0);
        }
    }

    // ---- reduce the 4 t-groups per bin ----
    red[g][binl] = acc;
    __syncthreads();
    if (tid < SB) {
        const float r0 = red[0][tid] + red[1][tid] + red[2][tid] + red[3][tid];
        out[((size_t)(b * N_VIEWS + v) << 9) + stile * SB + tid] = r0;
    }
}

extern "C" void kernel_launch(void* const* d_in, const int* in_sizes, int n_in,
                              void* d_out, int out_size, void* d_ws, size_t ws_size,
                              hipStream_t stream) {
    const float* img = (const float*)d_in[0];
    float* out = (float*)d_out;
    const int B = in_sizes[0] / (N_IMG * N_IMG);
    dim3 grid(N_VIEWS, B, N_BINS / SB);
    radon_fp_tiled<<<grid, 256, 0, stream>>>(img, out);
}

// Round 8
// 781.707 us; speedup vs baseline: 3.0353x; 1.5054x over previous
//
#include <hip/hip_runtime.h>

// Parallel-beam forward projection (Radon transform), LDS-tiled, v2.
// x: [B,1,512,512] f32 -> sino: [B,1,512,512] f32
// Block = (view, batch, 64-bin s-tile); 8 chunks of 64 t-steps.
// v2: 4-aligned X0 + interior fast-path staging (float4 loads, 9 granules/thread),
//     hoisted ray bases (inline-const j fma), float-mad LDS index.

#define N_IMG 512
#define N_VIEWS 512
#define N_BINS 512
#define SB 64      // bins per block
#define TC 64      // t-steps per chunk
#define NCH (N_IMG / TC)
#define TDIM 96    // staged tile dim (span <= 89.1 + 2 margin + 3 align < 96)
#define PITCH 97   // odd pitch: decorrelates LDS banks for most angles
#define GPR (TDIM / 4)            // granules per row = 24
#define NGRAN (TDIM * GPR)        // 2304 granules = 9 * 256

__global__ __launch_bounds__(256) void radon_fp_tiled2(const float* __restrict__ img,
                                                       float* __restrict__ out) {
    __shared__ float tile[TDIM * PITCH];
    __shared__ float red[4][SB];

    const int v     = blockIdx.x;   // view
    const int b     = blockIdx.y;   // batch
    const int stile = blockIdx.z;   // s-tile (0..7)
    const int tid   = threadIdx.x;
    const int binl  = tid & 63;     // bin within tile
    const int g     = tid >> 6;     // t-group (0..3)

    const float dth = (float)(3.14159265358979323846 / (double)N_VIEWS);
    float st, ct;
    sincosf((float)v * dth, &st, &ct);

    const float c = (float)(N_IMG - 1) * 0.5f;              // 255.5
    const float s = (float)(stile * SB + binl) - (float)(N_BINS - 1) * 0.5f;

    const float* __restrict__ im = img + (size_t)b * (N_IMG * N_IMG);

    // block-uniform s-range for bbox
    const float sA  = (float)(stile * SB) - (float)(N_BINS - 1) * 0.5f;
    const float sBv = sA + (float)(SB - 1);

    float acc = 0.0f;

    for (int ch = 0; ch < NCH; ++ch) {
        // ---- bounding box of this (s-tile, t-chunk) footprint (block-uniform) ----
        const float tA = (float)(ch * TC) - (float)(N_IMG - 1) * 0.5f;
        const float tB = tA + (float)(TC - 1);

        const float xs[4] = { sA * ct - tA * st, sA * ct - tB * st,
                              sBv * ct - tA * st, sBv * ct - tB * st };
        const float ys[4] = { sA * st + tA * ct, sA * st + tB * ct,
                              sBv * st + tA * ct, sBv * st + tB * ct };
        const float xmin = fminf(fminf(xs[0], xs[1]), fminf(xs[2], xs[3])) + c;
        const float ymin = fminf(fminf(ys[0], ys[1]), fminf(ys[2], ys[3])) + c;
        const int X0 = ((int)floorf(xmin) - 1) & ~3;   // -1 margin, 4-aligned down
        const int Y0 = (int)floorf(ymin) - 1;

        __syncthreads();   // previous chunk's reads done before overwrite

        // ---- stage TDIM x TDIM cells, zero outside the image ----
        const bool interior = (X0 >= 0) & (X0 + TDIM <= N_IMG) &
                              (Y0 >= 0) & (Y0 + TDIM <= N_IMG);
        if (interior) {
            // fast path: 2304 granules of 4, exactly 9 per thread; aligned float4 loads
#pragma unroll
            for (int k = 0; k < NGRAN / 256; ++k) {
                const int gi = tid + k * 256;
                const int r  = gi / GPR;
                const int gr = gi - r * GPR;
                const float4 vv = *reinterpret_cast<const float4*>(
                    im + ((Y0 + r) << 9) + X0 + 4 * gr);
                float* dst = &tile[r * PITCH + 4 * gr];
                dst[0] = vv.x; dst[1] = vv.y; dst[2] = vv.z; dst[3] = vv.w;
            }
        } else {
            // edge path: scalar with clamp+zero (exact reference semantics)
            for (int idx = tid; idx < TDIM * TDIM; idx += 256) {
                const int r  = idx / TDIM;
                const int cc = idx - r * TDIM;
                const int gx = X0 + cc;
                const int gy = Y0 + r;
                float val = 0.0f;
                if ((unsigned)gx < (unsigned)N_IMG && (unsigned)gy < (unsigned)N_IMG)
                    val = im[(gy << 9) + gx];
                tile[r * PITCH + cc] = val;
            }
        }
        __syncthreads();

        // ---- 16 t-steps per thread from LDS ----
        // hoist ray base for this (chunk, group): xl_j = xg - j*st, yl_j = yg + j*ct
        const float xbase = fmaf(s, ct, c - (float)X0);
        const float ybase = fmaf(s, st, c - (float)Y0);
        const float tb0 = (float)(ch * TC + g * 16) - (float)(N_IMG - 1) * 0.5f;
        const float xg = fmaf(-tb0, st, xbase);
        const float yg = fmaf(tb0, ct, ybase);
#pragma unroll
        for (int j = 0; j < 16; ++j) {
            const float xl = fmaf(-(float)j, st, xg);
            const float yl = fmaf((float)j, ct, yg);
            const float x0 = floorf(xl);
            const float y0 = floorf(yl);
            const float wx = xl - x0;
            const float wy = yl - y0;
            // exact integer index: y0*97 + x0 <= 9310 < 2^24
            const int e = (int)fmaf(y0, (float)PITCH, x0);
            const float* p = &tile[e];
            const float v00 = p[0];
            const float v10 = p[1];
            const float v01 = p[PITCH];
            const float v11 = p[PITCH + 1];
            const float a0 = fmaf(v10 - v00, wx, v00);
            const float a1 = fmaf(v11 - v01, wx, v01);
            acc += fmaf(a1 - a0, wy, a0);
        }
    }

    // ---- reduce the 4 t-groups per bin ----
    red[g][binl] = acc;
    __syncthreads();
    if (tid < SB) {
        const float r0 = red[0][tid] + red[1][tid] + red[2][tid] + red[3][tid];
        out[((size_t)(b * N_VIEWS + v) << 9) + stile * SB + tid] = r0;
    }
}

extern "C" void kernel_launch(void* const* d_in, const int* in_sizes, int n_in,
                              void* d_out, int out_size, void* d_ws, size_t ws_size,
                              hipStream_t stream) {
    const float* img = (const float*)d_in[0];
    float* out = (float*)d_out;
    const int B = in_sizes[0] / (N_IMG * N_IMG);
    dim3 grid(N_VIEWS, B, N_BINS / SB);
    radon_fp_tiled2<<<grid, 256, 0, stream>>>(img, out);
}

// Round 9
// 672.469 us; speedup vs baseline: 3.5284x; 1.1624x over previous
//
#include <hip/hip_runtime.h>

// Parallel-beam forward projection (Radon transform), LDS-tiled, v3.
// x: [B,1,512,512] f32 -> sino: [B,1,512,512] f32
// Block = (view, batch, 64-bin s-tile); 8 chunks of 64 t-steps.
// v3: staging writes remapped to 8x8 (row x granule-col) per wave so each
//     ds_write's banks = const + rl8 + 4*gl8 + q -> all 32 banks, 2-way (free).
//     Fully unrolled k-loop with compile-time sub-tile offsets.

#define N_IMG 512
#define N_VIEWS 512
#define N_BINS 512
#define SB 64      // bins per block
#define TC 64      // t-steps per chunk
#define NCH (N_IMG / TC)
#define TDIM 96    // staged tile dim (max sample offset ~93 < 96)
#define PITCH 97   // odd pitch: full 32-bank spread for near-axis angles
#define NGC 24     // granule (float4) columns per row

__global__ __launch_bounds__(256) void radon_fp_tiled3(const float* __restrict__ img,
                                                       float* __restrict__ out) {
    __shared__ float tile[TDIM * PITCH];
    __shared__ float red[4][SB];

    const int v     = blockIdx.x;   // view
    const int b     = blockIdx.y;   // batch
    const int stile = blockIdx.z;   // s-tile (0..7)
    const int tid   = threadIdx.x;
    const int binl  = tid & 63;     // bin within tile
    const int g     = tid >> 6;     // t-group == wave id (0..3)
    const int lane  = tid & 63;
    const int rl8   = lane >> 3;    // row offset within octet (0..7)
    const int gl8   = lane & 7;     // granule-col within octet (0..7)
    const int rbase = g * 24 + rl8; // each wave owns 24 rows of the 96

    const float dth = (float)(3.14159265358979323846 / (double)N_VIEWS);
    float st, ct;
    sincosf((float)v * dth, &st, &ct);

    const float c = (float)(N_IMG - 1) * 0.5f;              // 255.5
    const float s = (float)(stile * SB + binl) - (float)(N_BINS - 1) * 0.5f;

    const float* __restrict__ im = img + (size_t)b * (N_IMG * N_IMG);

    // block-uniform s-range for bbox
    const float sA  = (float)(stile * SB) - (float)(N_BINS - 1) * 0.5f;
    const float sBv = sA + (float)(SB - 1);

    float acc = 0.0f;

    for (int ch = 0; ch < NCH; ++ch) {
        // ---- bounding box of this (s-tile, t-chunk) footprint (block-uniform) ----
        const float tA = (float)(ch * TC) - (float)(N_IMG - 1) * 0.5f;
        const float tB = tA + (float)(TC - 1);

        const float xs[4] = { sA * ct - tA * st, sA * ct - tB * st,
                              sBv * ct - tA * st, sBv * ct - tB * st };
        const float ys[4] = { sA * st + tA * ct, sA * st + tB * ct,
                              sBv * st + tA * ct, sBv * st + tB * ct };
        const float xmin = fminf(fminf(xs[0], xs[1]), fminf(xs[2], xs[3])) + c;
        const float ymin = fminf(fminf(ys[0], ys[1]), fminf(ys[2], ys[3])) + c;
        const int X0 = ((int)floorf(xmin) - 1) & ~3;   // -1 margin, 4-aligned down
        const int Y0 = (int)floorf(ymin) - 1;

        __syncthreads();   // previous chunk's reads done before overwrite

        // ---- stage 96x96 cells (granules: 24 cols x 96 rows), zero outside ----
        const bool interior = (X0 >= 0) & (X0 + TDIM <= N_IMG) &
                              (Y0 >= 0) & (Y0 + TDIM <= N_IMG);
        if (interior) {
            // per-wave 8x8 (row x gcol) sub-block per unrolled k; banks 2-way (free)
            const float* gbase = im + ((Y0 + rbase) << 9) + X0 + 4 * gl8;
            float* lbase = &tile[rbase * PITCH + 4 * gl8];
#pragma unroll
            for (int k = 0; k < 9; ++k) {
                const int rb = (k / 3) * 8;          // compile-time
                const int gb = (k % 3) * 32;         // compile-time (8 granules * 4)
                const float4 vv = *reinterpret_cast<const float4*>(gbase + (rb << 9) + gb);
                float* dst = lbase + rb * PITCH + gb;
                dst[0] = vv.x; dst[1] = vv.y; dst[2] = vv.z; dst[3] = vv.w;
            }
        } else {
            // edge path: same mapping, per-element guard (exact zero-outside)
            const int gy0 = Y0 + rbase;
            const int gx0 = X0 + 4 * gl8;
#pragma unroll
            for (int k = 0; k < 9; ++k) {
                const int rb = (k / 3) * 8;
                const int gb = (k % 3) * 32;
                const int gy = gy0 + rb;
                float* dst = &tile[(rbase + rb) * PITCH + 4 * gl8 + gb];
                const bool rowok = ((unsigned)gy < (unsigned)N_IMG);
#pragma unroll
                for (int q = 0; q < 4; ++q) {
                    const int gx = gx0 + gb + q;
                    float val = 0.0f;
                    if (rowok && (unsigned)gx < (unsigned)N_IMG)
                        val = im[(gy << 9) + gx];
                    dst[q] = val;
                }
            }
        }
        __syncthreads();

        // ---- 16 t-steps per thread from LDS ----
        const float xbase = fmaf(s, ct, c - (float)X0);
        const float ybase = fmaf(s, st, c - (float)Y0);
        const float tb0 = (float)(ch * TC + g * 16) - (float)(N_IMG - 1) * 0.5f;
        const float xg = fmaf(-tb0, st, xbase);
        const float yg = fmaf(tb0, ct, ybase);
#pragma unroll
        for (int j = 0; j < 16; ++j) {
            const float xl = fmaf(-(float)j, st, xg);
            const float yl = fmaf((float)j, ct, yg);
            const float x0 = floorf(xl);
            const float y0 = floorf(yl);
            const float wx = xl - x0;
            const float wy = yl - y0;
            // exact integer index: y0*97 + x0 <= 9310 < 2^24
            const int e = (int)fmaf(y0, (float)PITCH, x0);
            const float* p = &tile[e];
            const float v00 = p[0];
            const float v10 = p[1];
            const float v01 = p[PITCH];
            const float v11 = p[PITCH + 1];
            const float a0 = fmaf(v10 - v00, wx, v00);
            const float a1 = fmaf(v11 - v01, wx, v01);
            acc += fmaf(a1 - a0, wy, a0);
        }
    }

    // ---- reduce the 4 t-groups per bin ----
    red[g][binl] = acc;
    __syncthreads();
    if (tid < SB) {
        const float r0 = red[0][tid] + red[1][tid] + red[2][tid] + red[3][tid];
        out[((size_t)(b * N_VIEWS + v) << 9) + stile * SB + tid] = r0;
    }
}

extern "C" void kernel_launch(void* const* d_in, const int* in_sizes, int n_in,
                              void* d_out, int out_size, void* d_ws, size_t ws_size,
                              hipStream_t stream) {
    const float* img = (const float*)d_in[0];
    float* out = (float*)d_out;
    const int B = in_sizes[0] / (N_IMG * N_IMG);
    dim3 grid(N_VIEWS, B, N_BINS / SB);
    radon_fp_tiled3<<<grid, 256, 0, stream>>>(img, out);
}